// Round 14
// baseline (1204.796 us; speedup 1.0000x reference)
//
#include <hip/hip_runtime.h>
#include <stddef.h>
#include <stdint.h>

// Elman RNN: out[t,b,u] = h_t = tanh(x_t @ Wx + h_{t-1} @ Wh + bias)
// B=128, T=512, D=128, U=512. Output [T, B, U] float32.
//
// pgemm (f16 dot2): P = x@Wx + bias -> d_out. (~15 us, validated)
// rnn HYBRID (r14): one WG (512 thr, 8 waves) per batch row; wave w owns
//   cols [64w, 64w+64). r13 was MFMA-throughput-bound (2480 cy/SIMD/step,
//   M=1 wastes 15/16 rows) while VALU sat idle (fdot2 = 64 MAC/cy/SIMD vs
//   M=1 MFMA 26.4). Split per wave:
//     tiles 0-2 (48 cols): MFMA. W = 38 frags in regs (pinned) + 10 in LDS.
//     tile  3  (16 cols): fdot2. 4 lanes/col x 128 k each, W = 64 dw pinned
//       arch VGPRs, reduce = shfl_xor(1)+shfl_xor(2).
//   New floors/SIMD: MFMA 96x19.4 = 1862 cy, VALU ~300 cy, DS ~1400 cy/CU.
//   h buffer: 4 quarters padded +16B so VALU's 4-address b128 broadcast
//   reads are bank-conflict-free. One barrier/step, parity dbuf.
//   Layouts (validated r10/r13, absmax 0.0039):
//     A[i][k]: lane = i + 16*(k/8), elem = k%8   (row 0 broadcast to all i)
//     B[k][j]: lane = j + 16*(k/8), elem = k%8
//     D[i][j]: lane = j + 16*(i/4), reg = i%4    (row 0 -> lanes 0-15, .x)

constexpr int B = 128;
constexpr int T = 512;
constexpr int D = 128;
constexpr int U = 512;

typedef _Float16 f16;
typedef _Float16 f16x2 __attribute__((ext_vector_type(2)));
typedef _Float16 f16x8 __attribute__((ext_vector_type(8)));
typedef __fp16   fp16x2 __attribute__((ext_vector_type(2)));
typedef float    f32x4 __attribute__((ext_vector_type(4)));
typedef unsigned int u32;

union U32H2 { u32 u; f16x2 h; fp16x2 p; };

static __device__ __forceinline__ u32 pk(float a, float b) {
    U32H2 c; c.p = __builtin_amdgcn_cvt_pkrtz(a, b); return c.u;
}

#if __has_builtin(__builtin_amdgcn_fdot2)
static __device__ __forceinline__ float fdot2(u32 a, u32 b, float c) {
    U32H2 x, y; x.u = a; y.u = b;
    return __builtin_amdgcn_fdot2(x.h, y.h, c, false);
}
#else
static __device__ __forceinline__ float fdot2(u32 a, u32 b, float c) {
    U32H2 x, y; x.u = a; y.u = b;
    return c + (float)x.h.x * (float)y.h.x + (float)x.h.y * (float)y.h.y;
}
#endif

static __device__ __forceinline__ float fast_tanh(float x) {
    float e = __expf(2.0f * x);
    return 1.0f - 2.0f * __builtin_amdgcn_rcpf(e + 1.0f);
}

// ---------------------------------------------------------------------------
// Kernel 1: P = x @ Wx + bias  (M=T*B, K=D=128 one-shot, N=U) — f16 dot2
// ---------------------------------------------------------------------------
__global__ __launch_bounds__(256) void pgemm_kernel(
    const float* __restrict__ x,     // [B, T, D]
    const float* __restrict__ Wx,    // [D, U]
    const float* __restrict__ bias,  // [U]
    float* __restrict__ P)           // [T*B, U]  (== d_out)
{
    __shared__ u32 xs[128][66];      // [row][k-pair]   (+2 pad)
    __shared__ u32 ws[64][132];      // [k-pair][col]   (+4 pad)

    const int rb  = blockIdx.x;
    const int cb  = blockIdx.y;
    const int tid = threadIdx.x;
    const int tr  = tid >> 4;
    const int tcc = tid & 15;

    const float4* x4 = (const float4*)x;
#pragma unroll
    for (int l = 0; l < 16; ++l) {
        int idx = tid + l * 256;
        int r   = idx >> 5;
        int q   = idx & 31;
        int m   = rb * 128 + r;
        int b_  = m & 127;
        int t_  = m >> 7;
        float4 v = x4[((size_t)b_ * T + t_) * 32 + q];
        xs[r][2 * q]     = pk(v.x, v.y);
        xs[r][2 * q + 1] = pk(v.z, v.w);
    }
    const float4* W4 = (const float4*)Wx;
#pragma unroll
    for (int l = 0; l < 8; ++l) {
        int idx = tid + l * 256;
        int kp  = idx >> 5;
        int q   = idx & 31;
        float4 a = W4[(size_t)(2 * kp)     * 128 + cb * 32 + q];
        float4 c = W4[(size_t)(2 * kp + 1) * 128 + cb * 32 + q];
        uint4 w;
        w.x = pk(a.x, c.x); w.y = pk(a.y, c.y);
        w.z = pk(a.z, c.z); w.w = pk(a.w, c.w);
        *(uint4*)&ws[kp][4 * q] = w;
    }
    __syncthreads();

    float acc[8][8];
#pragma unroll
    for (int i = 0; i < 8; ++i)
#pragma unroll
        for (int j = 0; j < 8; ++j) acc[i][j] = 0.f;

#pragma unroll 2
    for (int kp = 0; kp < 64; ++kp) {
        u32 xv[8], wv[8];
#pragma unroll
        for (int i = 0; i < 8; ++i) xv[i] = xs[tr + 16 * i][kp];
#pragma unroll
        for (int j = 0; j < 8; ++j) wv[j] = ws[kp][tcc + 16 * j];
#pragma unroll
        for (int i = 0; i < 8; ++i)
#pragma unroll
            for (int j = 0; j < 8; ++j)
                acc[i][j] = fdot2(xv[i], wv[j], acc[i][j]);
    }

#pragma unroll
    for (int j = 0; j < 8; ++j) {
        int c    = cb * 128 + tcc + 16 * j;
        float bv = bias[c];
#pragma unroll
        for (int i = 0; i < 8; ++i) {
            int m = rb * 128 + tr + 16 * i;
            P[(size_t)m * U + c] = acc[i][j] + bv;
        }
    }
}

// ---------------------------------------------------------------------------
// Kernel 2: hybrid MFMA+fdot2 recurrence, one WG (512 thr) per batch row.
// ---------------------------------------------------------------------------
__global__ __launch_bounds__(512, 2) void rnn_kernel(
    const float* __restrict__ Wh,    // [U, U] f32
    float* __restrict__ out)         // [T*B, U]; P on entry, h on exit
{
    // WL: 10 LDS frags per wave (tile 2, slabs 6..15): 80 KB
    __shared__ __align__(16) u32 WL[20480];
    // hbuf: f16 h, 4 quarters of 128 k padded to 272 B (=136 f16, 68 u32)
    __shared__ __align__(16) u32 hbuf[2][272];

    const int tid = threadIdx.x;
    const int w   = tid >> 6;        // wave 0..7 (cols 64w..64w+63)
    const int l   = tid & 63;        // lane
    const int lg  = l >> 4;          // k-octet group 0..3 (MFMA operands)
    const int lc  = l & 15;          // col-in-tile
    const int q   = l & 3;           // VALU k-quarter
    const int vcol= 48 + (l >> 2);   // VALU col within wave (lane group of 4)
    const int b   = blockIdx.x;
    const int cb  = 64 * w;          // wave col base

    // ---- init: MFMA B-frags, tiles 0,1 (all 16 slabs) + tile 2 slabs 0..5 ----
    // frag(ct, s) elem e = Wh[32s + 8*lg + e][cb + 16ct + lc]
    f16x8 Wf0[16], Wf1[16], Wf2[6];
#pragma unroll
    for (int s = 0; s < 16; ++s) {
        const float* s0 = Wh + (size_t)(32 * s + 8 * lg) * U + cb + lc;
        f16x8 f0, f1;
#pragma unroll
        for (int e = 0; e < 8; ++e) {
            f0[e] = (f16)s0[(size_t)e * U];
            f1[e] = (f16)s0[(size_t)e * U + 16];
        }
        Wf0[s] = f0; Wf1[s] = f1;
    }
#pragma unroll
    for (int s = 0; s < 6; ++s) {
        const float* s0 = Wh + (size_t)(32 * s + 8 * lg) * U + cb + 32 + lc;
        f16x8 f;
#pragma unroll
        for (int e = 0; e < 8; ++e) f[e] = (f16)s0[(size_t)e * U];
        Wf2[s] = f;
    }
    // PIN: opaque defs -> no remat-from-global inside the t-loop (r13 lesson)
#pragma unroll
    for (int s = 0; s < 16; ++s) { asm("" : "+v"(Wf0[s])); asm("" : "+v"(Wf1[s])); }
#pragma unroll
    for (int s = 0; s < 6; ++s)  { asm("" : "+v"(Wf2[s])); }

    // ---- init: VALU W for tile 3: lane owns col cb+vcol, k in [128q,128q+128)
    u32 Wv[64];
    {
        const float* c0 = Wh + (size_t)(q * 128) * U + cb + vcol;
#pragma unroll
        for (int j = 0; j < 64; ++j)
            Wv[j] = pk(c0[(size_t)(2 * j) * U], c0[(size_t)(2 * j + 1) * U]);
#pragma unroll
        for (int j = 0; j < 64; ++j) asm("" : "+v"(Wv[j]));
    }

    // ---- init: LDS frags (tile 2, slabs 6..15) ----
#pragma unroll
    for (int sr = 0; sr < 10; ++sr) {
        const float* s0 = Wh + (size_t)(32 * (6 + sr) + 8 * lg) * U + cb + 32 + lc;
        f16x8 f;
#pragma unroll
        for (int e = 0; e < 8; ++e) f[e] = (f16)s0[(size_t)e * U];
        *(f16x8*)&WL[((w * 10 + sr) * 64 + l) * 4] = f;
    }

    // h_0 = 0 (both parities)
    if (tid < 272) { hbuf[0][tid] = 0u; hbuf[1][tid] = 0u; }
    __syncthreads();

    float* outb = out + (size_t)b * U;

    // P prefetch for t=0
    float pv0 = 0.f, pv1 = 0.f, pv2 = 0.f, pvv = 0.f;
    if (l < 16) {
        pv0 = outb[cb + 0  + lc];
        pv1 = outb[cb + 16 + lc];
        pv2 = outb[cb + 32 + lc];
    }
    if (q == 0) pvv = outb[cb + vcol];

    for (int t = 0; t < T; ++t) {
        const int par = t & 1;
        const f16* hb  = (const f16*)hbuf[par];
        const u32* hbu = hbuf[par];

        f32x4 acc0 = (f32x4)0.f, acc1 = (f32x4)0.f, acc2 = (f32x4)0.f;
        float accv = 0.f;

        // A-frag for slab s: h f16 at padded idx16 = (s>>2)*136 + (s&3)*32 + 8lg
#define ALOAD(s) (*(const f16x8*)&hb[((s) >> 2) * 136 + ((s) & 3) * 32 + 8 * lg])

#pragma unroll
        for (int s = 0; s < 16; ++s) {
            // VALU h chunk: 4 distinct addrs (q), stride 68 u32 -> banks differ
            uint4 hq = *(const uint4*)&hbu[q * 68 + 4 * s];
            f16x8 a = ALOAD(s);
            acc0 = __builtin_amdgcn_mfma_f32_16x16x32_f16(a, Wf0[s], acc0, 0, 0, 0);
            acc1 = __builtin_amdgcn_mfma_f32_16x16x32_f16(a, Wf1[s], acc1, 0, 0, 0);
            f16x8 b2 = (s < 6) ? Wf2[s]
                     : *(const f16x8*)&WL[((w * 10 + (s - 6)) * 64 + l) * 4];
            acc2 = __builtin_amdgcn_mfma_f32_16x16x32_f16(a, b2, acc2, 0, 0, 0);
            // tile 3 via fdot2 (k = 128q + 8s + {0..7})
            accv = fdot2(hq.x, Wv[4 * s + 0], accv);
            accv = fdot2(hq.y, Wv[4 * s + 1], accv);
            accv = fdot2(hq.z, Wv[4 * s + 2], accv);
            accv = fdot2(hq.w, Wv[4 * s + 3], accv);
        }
#undef ALOAD

        // reduce tile-3 partials within each 4-lane group
        accv += __shfl_xor(accv, 1);
        accv += __shfl_xor(accv, 2);

        float* prow = outb + (size_t)t * (B * U);
        const float* prown = outb + (size_t)((t + 1 < T) ? t + 1 : t) * (B * U);
        f16* hbn = (f16*)hbuf[par ^ 1];

        float nv0 = 0.f, nv1 = 0.f, nv2 = 0.f, nvv = 0.f;
        if (l < 16) {
            float h0 = fast_tanh(pv0 + acc0.x);
            float h1 = fast_tanh(pv1 + acc1.x);
            float h2 = fast_tanh(pv2 + acc2.x);
            int c0 = cb + lc, c1 = cb + 16 + lc, c2 = cb + 32 + lc;
            prow[c0] = h0; prow[c1] = h1; prow[c2] = h2;
            hbn[(c0 >> 7) * 136 + (c0 & 127)] = (f16)h0;
            hbn[(c1 >> 7) * 136 + (c1 & 127)] = (f16)h1;
            hbn[(c2 >> 7) * 136 + (c2 & 127)] = (f16)h2;
            nv0 = prown[c0]; nv1 = prown[c1]; nv2 = prown[c2];
        }
        if (q == 0) {
            int c3 = cb + vcol;
            float hv = fast_tanh(pvv + accv);
            prow[c3] = hv;
            hbn[(c3 >> 7) * 136 + (c3 & 127)] = (f16)hv;
            nvv = prown[c3];
        }

        __syncthreads();   // h(par^1) visible for next step
        pv0 = nv0; pv1 = nv1; pv2 = nv2; pvv = nvv;
    }
}

// ---------------------------------------------------------------------------
extern "C" void kernel_launch(void* const* d_in, const int* in_sizes, int n_in,
                              void* d_out, int out_size, void* d_ws, size_t ws_size,
                              hipStream_t stream)
{
    (void)d_ws; (void)ws_size; (void)in_sizes; (void)n_in; (void)out_size;
    const float* x    = (const float*)d_in[0];  // [B, T, D]
    const float* Wx   = (const float*)d_in[1];  // [D, U]
    const float* Wh   = (const float*)d_in[2];  // [U, U]
    const float* bias = (const float*)d_in[3];  // [U]
    float* out = (float*)d_out;                 // [T, B, U]

    pgemm_kernel<<<dim3((T * B) / 128, U / 128), 256, 0, stream>>>(x, Wx, bias, out);
    rnn_kernel<<<B, 512, 0, stream>>>(Wh, out);
}

// Round 15
// 900.953 us; speedup vs baseline: 1.3372x; 1.3372x over previous
//
#include <hip/hip_runtime.h>
#include <stddef.h>
#include <stdint.h>

// Elman RNN: out[t,b,u] = h_t = tanh(x_t @ Wx + h_{t-1} @ Wh + bias)
// B=128, T=512, D=128, U=512. Output [T, B, U] float32.
//
// pgemm (f16 dot2): P = x@Wx + bias -> d_out. (~15 us, validated)
// rnn (builtin MFMA, r13 structure + r15 prefetch hoist): one WG (512 thr,
//   8 waves) per batch row. Wave w owns cols [64w, 64w+64) = 4 col-tiles.
//   64 MFMAs/wave/step; W = 48 frags register-resident (pinned) + 16 in LDS.
//   r15 change vs r13 (836 us): next-step P prefetch issued at TOP of the
//   loop so its ~200-900cy latency hides under the ~2500cy MFMA phase
//   (r13 issued it in the tail; __syncthreads' vmcnt(0) drain put it naked
//   on the serial critical path every step).
//   History: hybrid MFMA+fdot2 (r14) regressed — VALU-consumed W lives in
//   AGPRs -> v_accvgpr_read tax (the repeated lesson of rounds 3-10,14).
//   Layouts (validated r10/r13, absmax 0.0039):
//     A[i][k]: lane = i + 16*(k/8), elem = k%8   (row 0 broadcast to all i)
//     B[k][j]: lane = j + 16*(k/8), elem = k%8
//     D[i][j]: lane = j + 16*(i/4), reg = i%4    (row 0 -> lanes 0-15, .x)

constexpr int B = 128;
constexpr int T = 512;
constexpr int D = 128;
constexpr int U = 512;

typedef _Float16 f16;
typedef _Float16 f16x2 __attribute__((ext_vector_type(2)));
typedef _Float16 f16x8 __attribute__((ext_vector_type(8)));
typedef __fp16   fp16x2 __attribute__((ext_vector_type(2)));
typedef float    f32x4 __attribute__((ext_vector_type(4)));
typedef unsigned int u32;

union U32H2 { u32 u; f16x2 h; fp16x2 p; };

static __device__ __forceinline__ u32 pk(float a, float b) {
    U32H2 c; c.p = __builtin_amdgcn_cvt_pkrtz(a, b); return c.u;
}

#if __has_builtin(__builtin_amdgcn_fdot2)
static __device__ __forceinline__ float fdot2(u32 a, u32 b, float c) {
    U32H2 x, y; x.u = a; y.u = b;
    return __builtin_amdgcn_fdot2(x.h, y.h, c, false);
}
#else
static __device__ __forceinline__ float fdot2(u32 a, u32 b, float c) {
    U32H2 x, y; x.u = a; y.u = b;
    return c + (float)x.h.x * (float)y.h.x + (float)x.h.y * (float)y.h.y;
}
#endif

static __device__ __forceinline__ float fast_tanh(float x) {
    float e = __expf(2.0f * x);
    return 1.0f - 2.0f * __builtin_amdgcn_rcpf(e + 1.0f);
}

// ---------------------------------------------------------------------------
// Kernel 1: P = x @ Wx + bias  (M=T*B, K=D=128 one-shot, N=U) — f16 dot2
// ---------------------------------------------------------------------------
__global__ __launch_bounds__(256) void pgemm_kernel(
    const float* __restrict__ x,     // [B, T, D]
    const float* __restrict__ Wx,    // [D, U]
    const float* __restrict__ bias,  // [U]
    float* __restrict__ P)           // [T*B, U]  (== d_out)
{
    __shared__ u32 xs[128][66];      // [row][k-pair]   (+2 pad)
    __shared__ u32 ws[64][132];      // [k-pair][col]   (+4 pad)

    const int rb  = blockIdx.x;
    const int cb  = blockIdx.y;
    const int tid = threadIdx.x;
    const int tr  = tid >> 4;
    const int tcc = tid & 15;

    const float4* x4 = (const float4*)x;
#pragma unroll
    for (int l = 0; l < 16; ++l) {
        int idx = tid + l * 256;
        int r   = idx >> 5;
        int q   = idx & 31;
        int m   = rb * 128 + r;
        int b_  = m & 127;
        int t_  = m >> 7;
        float4 v = x4[((size_t)b_ * T + t_) * 32 + q];
        xs[r][2 * q]     = pk(v.x, v.y);
        xs[r][2 * q + 1] = pk(v.z, v.w);
    }
    const float4* W4 = (const float4*)Wx;
#pragma unroll
    for (int l = 0; l < 8; ++l) {
        int idx = tid + l * 256;
        int kp  = idx >> 5;
        int q   = idx & 31;
        float4 a = W4[(size_t)(2 * kp)     * 128 + cb * 32 + q];
        float4 c = W4[(size_t)(2 * kp + 1) * 128 + cb * 32 + q];
        uint4 w;
        w.x = pk(a.x, c.x); w.y = pk(a.y, c.y);
        w.z = pk(a.z, c.z); w.w = pk(a.w, c.w);
        *(uint4*)&ws[kp][4 * q] = w;
    }
    __syncthreads();

    float acc[8][8];
#pragma unroll
    for (int i = 0; i < 8; ++i)
#pragma unroll
        for (int j = 0; j < 8; ++j) acc[i][j] = 0.f;

#pragma unroll 2
    for (int kp = 0; kp < 64; ++kp) {
        u32 xv[8], wv[8];
#pragma unroll
        for (int i = 0; i < 8; ++i) xv[i] = xs[tr + 16 * i][kp];
#pragma unroll
        for (int j = 0; j < 8; ++j) wv[j] = ws[kp][tcc + 16 * j];
#pragma unroll
        for (int i = 0; i < 8; ++i)
#pragma unroll
            for (int j = 0; j < 8; ++j)
                acc[i][j] = fdot2(xv[i], wv[j], acc[i][j]);
    }

#pragma unroll
    for (int j = 0; j < 8; ++j) {
        int c    = cb * 128 + tcc + 16 * j;
        float bv = bias[c];
#pragma unroll
        for (int i = 0; i < 8; ++i) {
            int m = rb * 128 + tr + 16 * i;
            P[(size_t)m * U + c] = acc[i][j] + bv;
        }
    }
}

// ---------------------------------------------------------------------------
// Kernel 2: recurrence via MFMA, one WG (512 thr) per batch row.
// ---------------------------------------------------------------------------
__global__ __launch_bounds__(512, 2) void rnn_kernel(
    const float* __restrict__ Wh,    // [U, U] f32
    float* __restrict__ out)         // [T*B, U]; P on entry, h on exit
{
    __shared__ __align__(16) u32 WL[32768];      // 128 KB: W frags s=12..15
    __shared__ __align__(16) u32 hbuf[2][256];   // h f16 [2 parity][512]

    const int tid = threadIdx.x;
    const int w   = tid >> 6;        // wave 0..7 (owns cols 64w..64w+63)
    const int l   = tid & 63;        // lane
    const int lg  = l >> 4;          // k-octet group 0..3
    const int lc  = l & 15;          // col-in-tile
    const int b   = blockIdx.x;

    // ---- init: B-fragments of Wh (f32 -> f16) ----
    // frag(ct, s) elem e = Wh[32s + 8*lg + e][64w + 16ct + lc]
    f16x8 Wf[4][12];                 // slabs 0..11 -> register-resident
#pragma unroll
    for (int ct = 0; ct < 4; ++ct) {
#pragma unroll
        for (int s = 0; s < 12; ++s) {
            const float* src = Wh + (size_t)(32 * s + 8 * lg) * U
                             + 64 * w + 16 * ct + lc;
            f16x8 f;
#pragma unroll
            for (int e = 0; e < 8; ++e) f[e] = (f16)src[(size_t)e * U];
            Wf[ct][s] = f;
        }
    }
    // PIN: opaque def -> compiler cannot rematerialize Wf from global inside
    // the t-loop (round 10's hidden cost: FETCH 92.5MB = per-step W reloads).
#pragma unroll
    for (int ct = 0; ct < 4; ++ct)
#pragma unroll
        for (int s = 0; s < 12; ++s)
            asm("" : "+v"(Wf[ct][s]));

    // slabs 12..15 -> LDS, slot = (w*16 + sr*4 + ct), 16 B per lane
#pragma unroll
    for (int sr = 0; sr < 4; ++sr) {
#pragma unroll
        for (int ct = 0; ct < 4; ++ct) {
            const float* src = Wh + (size_t)(32 * (12 + sr) + 8 * lg) * U
                             + 64 * w + 16 * ct + lc;
            f16x8 f;
#pragma unroll
            for (int e = 0; e < 8; ++e) f[e] = (f16)src[(size_t)e * U];
            *(f16x8*)&WL[((w * 16 + sr * 4 + ct) * 64 + l) * 4] = f;
        }
    }

    if (tid < 256) { hbuf[0][tid] = 0u; hbuf[1][tid] = 0u; }
    __syncthreads();

    float* outb = out + (size_t)b * U;

    // P prefetch for t=0 (lanes 0-15 of each wave own cols 64w+16ct+lc)
    float pv0 = 0.f, pv1 = 0.f, pv2 = 0.f, pv3 = 0.f;
    if (l < 16) {
        pv0 = outb[64 * w + 0  + lc];
        pv1 = outb[64 * w + 16 + lc];
        pv2 = outb[64 * w + 32 + lc];
        pv3 = outb[64 * w + 48 + lc];
    }

    for (int t = 0; t < T; ++t) {
        const int par = t & 1;
        const f16* hb = (const f16*)hbuf[par];

        // r15: issue next-step P prefetch FIRST — its global latency hides
        // under the whole MFMA phase instead of stalling the pre-barrier
        // vmcnt(0) drain in the tail.
        float nv0 = 0.f, nv1 = 0.f, nv2 = 0.f, nv3 = 0.f;
        {
            const float* prown = outb + (size_t)((t + 1 < T) ? t + 1 : t) * (B * U);
            if (l < 16) {
                nv0 = prown[64 * w + 0  + lc];
                nv1 = prown[64 * w + 16 + lc];
                nv2 = prown[64 * w + 32 + lc];
                nv3 = prown[64 * w + 48 + lc];
            }
        }

        f32x4 acc0 = (f32x4)0.f, acc1 = (f32x4)0.f;
        f32x4 acc2 = (f32x4)0.f, acc3 = (f32x4)0.f;

        // A-frag: whole-wave broadcast of h octet (rows 1..15 of A are
        // harmless copies; only D row 0 is consumed).
#define ALOAD(s) (*(const f16x8*)&hb[32 * (s) + 8 * lg])
#define WLREAD(fi) (*(const f16x8*)&WL[((w * 16 + (fi)) * 64 + l) * 4])

        // 4 groups: {issue 4 LDS frag reads} {3 register slabs} {consume}
#pragma unroll
        for (int g = 0; g < 4; ++g) {
            f16x8 b0 = WLREAD(4 * g + 0);
            f16x8 b1 = WLREAD(4 * g + 1);
            f16x8 b2 = WLREAD(4 * g + 2);
            f16x8 b3 = WLREAD(4 * g + 3);
#pragma unroll
            for (int s = 3 * g; s < 3 * g + 3; ++s) {
                f16x8 a = ALOAD(s);
                acc0 = __builtin_amdgcn_mfma_f32_16x16x32_f16(a, Wf[0][s], acc0, 0, 0, 0);
                acc1 = __builtin_amdgcn_mfma_f32_16x16x32_f16(a, Wf[1][s], acc1, 0, 0, 0);
                acc2 = __builtin_amdgcn_mfma_f32_16x16x32_f16(a, Wf[2][s], acc2, 0, 0, 0);
                acc3 = __builtin_amdgcn_mfma_f32_16x16x32_f16(a, Wf[3][s], acc3, 0, 0, 0);
            }
            f16x8 a = ALOAD(12 + g);
            acc0 = __builtin_amdgcn_mfma_f32_16x16x32_f16(a, b0, acc0, 0, 0, 0);
            acc1 = __builtin_amdgcn_mfma_f32_16x16x32_f16(a, b1, acc1, 0, 0, 0);
            acc2 = __builtin_amdgcn_mfma_f32_16x16x32_f16(a, b2, acc2, 0, 0, 0);
            acc3 = __builtin_amdgcn_mfma_f32_16x16x32_f16(a, b3, acc3, 0, 0, 0);
        }
#undef ALOAD
#undef WLREAD

        // tail: row 0 of D lives in lanes 0-15, reg .x
        if (l < 16) {
            float* prow = outb + (size_t)t * (B * U);
            f16* hbn = (f16*)hbuf[par ^ 1];

            float h0 = fast_tanh(pv0 + acc0.x);
            float h1 = fast_tanh(pv1 + acc1.x);
            float h2 = fast_tanh(pv2 + acc2.x);
            float h3 = fast_tanh(pv3 + acc3.x);
            prow[64 * w + 0  + lc] = h0;
            prow[64 * w + 16 + lc] = h1;
            prow[64 * w + 32 + lc] = h2;
            prow[64 * w + 48 + lc] = h3;
            hbn[64 * w + 0  + lc] = (f16)h0;
            hbn[64 * w + 16 + lc] = (f16)h1;
            hbn[64 * w + 32 + lc] = (f16)h2;
            hbn[64 * w + 48 + lc] = (f16)h3;
        }

        __syncthreads();   // h(par^1) visible for next step
        pv0 = nv0; pv1 = nv1; pv2 = nv2; pv3 = nv3;
    }
}

// ---------------------------------------------------------------------------
extern "C" void kernel_launch(void* const* d_in, const int* in_sizes, int n_in,
                              void* d_out, int out_size, void* d_ws, size_t ws_size,
                              hipStream_t stream)
{
    (void)d_ws; (void)ws_size; (void)in_sizes; (void)n_in; (void)out_size;
    const float* x    = (const float*)d_in[0];  // [B, T, D]
    const float* Wx   = (const float*)d_in[1];  // [D, U]
    const float* Wh   = (const float*)d_in[2];  // [U, U]
    const float* bias = (const float*)d_in[3];  // [U]
    float* out = (float*)d_out;                 // [T, B, U]

    pgemm_kernel<<<dim3((T * B) / 128, U / 128), 256, 0, stream>>>(x, Wx, bias, out);
    rnn_kernel<<<B, 512, 0, stream>>>(Wh, out);
}